// Round 1
// baseline (318.641 us; speedup 1.0000x reference)
//
#include <hip/hip_runtime.h>
#include <cstdint>
#include <cstddef>

#define BB 32
#define NN 8400
#define NCC 80
#define MM 40
#define RM 16
#define TOPKK 10

// ---------- helpers ----------
__device__ __forceinline__ float sigmoidf_(float x) { return 1.0f / (1.0f + expf(-x)); }
__device__ __forceinline__ float softplusf_(float x) {
    return fmaxf(x, 0.0f) + log1pf(expf(-fabsf(x)));
}
__device__ __forceinline__ void anchor_xy(int n, float& ax, float& ay) {
    int s, x, y;
    if (n < 6400)      { s = 8;  y = n / 80;            x = n - y * 80; }
    else if (n < 8000) { int i = n - 6400; s = 16; y = i / 40; x = i - y * 40; }
    else               { int i = n - 8000; s = 32; y = i / 20; x = i - y * 20; }
    ax = ((float)x + 0.5f) * (float)s;
    ay = ((float)y + 0.5f) * (float)s;
}

// ---------- K2: DFL softmax-dot -> pred_bboxes ----------
__global__ __launch_bounds__(256) void k_dfl(const float* __restrict__ pd,
                                             const float* __restrict__ w,
                                             float* __restrict__ pbb) {
    int g = blockIdx.x * 256 + threadIdx.x;
    if (g >= BB * NN * 4) return;
    const float* p = pd + (size_t)g * RM;
    float x[RM];
    #pragma unroll
    for (int i = 0; i < 4; i++) {
        float4 v = *(const float4*)(p + i * 4);
        x[i*4+0] = v.x; x[i*4+1] = v.y; x[i*4+2] = v.z; x[i*4+3] = v.w;
    }
    float mx = x[0];
    #pragma unroll
    for (int i = 1; i < RM; i++) mx = fmaxf(mx, x[i]);
    float s = 0.f, d = 0.f;
    #pragma unroll
    for (int i = 0; i < RM; i++) {
        float e = expf(x[i] - mx);
        s += e; d += e * w[i];
    }
    float val = d / s;
    int bn = g >> 2, side = g & 3;
    int n = bn % NN;
    float ax, ay; anchor_xy(n, ax, ay);
    float coord = (side == 0) ? ax - val : (side == 1) ? ay - val
                : (side == 2) ? ax + val : ay + val;
    pbb[g] = coord;
}

// ---------- K3: align tile + column-max + fused softplus sum ----------
// grid: (ceil(N/128), B), 256 threads. Threads split: nloc = t&127, m-half = t>>7.
#define SCS 81   // LDS stride for sigmoid tile; gcd(81,32)=1 -> conflict-free gathers
__global__ __launch_bounds__(256) void k_align(const float* __restrict__ ps,
                                               const int*   __restrict__ gl,
                                               const float* __restrict__ gb,
                                               const float* __restrict__ pbb,
                                               float* __restrict__ algn,
                                               float* __restrict__ maxm,
                                               float* __restrict__ accum) {
    __shared__ float sc[128 * SCS];
    __shared__ float gtb[MM * 4];
    __shared__ int   glab[MM];
    __shared__ float cm[256];
    __shared__ float redf[4];
    const int b  = blockIdx.y;
    const int n0 = blockIdx.x * 128;
    const int t  = threadIdx.x;

    if (t < MM * 4)            gtb[t] = gb[b * MM * 4 + t];
    else if (t < MM * 4 + MM)  glab[t - MM * 4] = gl[b * MM + (t - MM * 4)];

    // phase 1: load 128x80 score tile, sigmoid into LDS, accumulate softplus
    float sp = 0.f;
    #pragma unroll
    for (int k = 0; k < 10; k++) {
        int f = t + k * 256;           // [0,2560)
        int row = f / 20, c4 = f - row * 20;
        int n = n0 + row;
        if (n < NN) {
            float4 v = *(const float4*)(ps + ((size_t)(b * NN + n)) * NCC + c4 * 4);
            sp += softplusf_(v.x) + softplusf_(v.y) + softplusf_(v.z) + softplusf_(v.w);
            int base = row * SCS + c4 * 4;
            sc[base + 0] = sigmoidf_(v.x);
            sc[base + 1] = sigmoidf_(v.y);
            sc[base + 2] = sigmoidf_(v.z);
            sc[base + 3] = sigmoidf_(v.w);
        }
    }
    __syncthreads();

    // phase 2: align for 20 gts per thread-half, running column max
    const int nloc = t & 127;
    const int n    = n0 + nloc;
    const int mb   = (t >> 7) * 20;
    float cmax = -INFINITY;
    if (n < NN) {
        float4 p4 = *(const float4*)(pbb + ((size_t)(b * NN + n)) * 4);
        const float px1 = p4.x, py1 = p4.y, px2 = p4.z, py2 = p4.w;
        const float a1 = (px2 - px1) * (py2 - py1);
        #pragma unroll
        for (int j = 0; j < 20; j++) {
            int m = mb + j;
            float gx1 = gtb[m*4+0], gy1 = gtb[m*4+1], gx2 = gtb[m*4+2], gy2 = gtb[m*4+3];
            float a2 = (gx2 - gx1) * (gy2 - gy1);
            float iw = fmaxf(fminf(px2, gx2) - fmaxf(px1, gx1), 0.f);
            float ih = fmaxf(fminf(py2, gy2) - fmaxf(py1, gy1), 0.f);
            float inter = iw * ih;
            float iou = inter / (a1 + a2 - inter + 1e-16f);
            iou = fmaxf(iou, 0.f);
            float sg = sc[nloc * SCS + glab[m]];
            float i2 = iou * iou;
            float al = sqrtf(sg) * (i2 * i2 * i2);
            algn[((size_t)(b * MM + m)) * NN + n] = al;
            cmax = fmaxf(cmax, al);
        }
    }
    cm[t] = cmax;
    __syncthreads();
    if (t < 128 && n < NN) maxm[(size_t)b * NN + n] = fmaxf(cm[t], cm[t + 128]);

    // softplus block reduction -> one atomic
    #pragma unroll
    for (int off = 32; off > 0; off >>= 1) sp += __shfl_down(sp, off);
    if ((t & 63) == 0) redf[t >> 6] = sp;
    __syncthreads();
    if (t == 0) atomicAdd(accum, redf[0] + redf[1] + redf[2] + redf[3]);
}

// ---------- K4: top-10 per (b,m) row, min-index tie-break ----------
__global__ __launch_bounds__(256) void k_topk(const float* __restrict__ algn,
                                              float* __restrict__ cval,
                                              int*   __restrict__ cidx) {
    __shared__ __align__(16) float row[NN];
    __shared__ unsigned long long redk[4];
    const int bm = blockIdx.x;
    const int t  = threadIdx.x;
    const float* src = algn + (size_t)bm * NN;
    for (int f = t; f < NN / 4; f += 256)
        ((float4*)row)[f] = ((const float4*)src)[f];
    __syncthreads();

    for (int pass = 0; pass < TOPKK; pass++) {
        unsigned long long best = 0ull;
        for (int i = t; i < NN; i += 256) {
            unsigned int vb = __float_as_uint(row[i]);
            unsigned int k32 = (vb & 0x80000000u) ? ~vb : (vb | 0x80000000u);
            unsigned long long key =
                ((unsigned long long)k32 << 32) |
                (unsigned long long)(0xFFFFFFFFu - (unsigned int)i);
            best = key > best ? key : best;
        }
        #pragma unroll
        for (int off = 32; off > 0; off >>= 1) {
            unsigned long long o = __shfl_down(best, off);
            best = o > best ? o : best;
        }
        if ((t & 63) == 0) redk[t >> 6] = best;
        __syncthreads();
        if (t == 0) {
            unsigned long long bb = redk[0];
            #pragma unroll
            for (int wv = 1; wv < 4; wv++) bb = redk[wv] > bb ? redk[wv] : bb;
            int idx = (int)(0xFFFFFFFFu - (unsigned int)(bb & 0xFFFFFFFFull));
            cval[bm * TOPKK + pass] = row[idx];
            cidx[bm * TOPKK + pass] = idx;
            row[idx] = -INFINITY;
        }
        __syncthreads();
    }
}

// ---------- K5: candidate filter -> per-anchor min gt index ----------
__global__ __launch_bounds__(256) void k_select(const float* __restrict__ cval,
                                                const int*   __restrict__ cidx,
                                                const float* __restrict__ maxm,
                                                int* __restrict__ tgt) {
    int c = blockIdx.x * 256 + threadIdx.x;
    if (c >= BB * MM * TOPKK) return;
    int b = c / (MM * TOPKK);
    int m = (c / TOPKK) % MM;
    float v = cval[c];
    int n = cidx[c];
    if (v > 1e-9f && v == maxm[(size_t)b * NN + n])
        atomicMin(&tgt[(size_t)b * NN + n], m);
}

// ---------- K6: fg accumulation (dot, box, count) ----------
__global__ __launch_bounds__(256) void k_fg(const int*   __restrict__ tgt,
                                            const int*   __restrict__ gl,
                                            const float* __restrict__ gb,
                                            const float* __restrict__ ps,
                                            const float* __restrict__ pbb,
                                            const float* __restrict__ maxm,
                                            float* __restrict__ accum) {
    int i = blockIdx.x * 256 + threadIdx.x;   // i in [0, B*N)
    int tg = tgt[i];
    if (tg >= MM) return;
    int b = i / NN;
    int lab = gl[b * MM + tg];
    float x = ps[(size_t)i * NCC + lab];
    float mm = maxm[i];
    float4 p = *(const float4*)(pbb + (size_t)i * 4);
    const float* g = gb + ((size_t)b * MM + tg) * 4;
    float a1 = (p.z - p.x) * (p.w - p.y);
    float a2 = (g[2] - g[0]) * (g[3] - g[1]);
    float iw = fmaxf(fminf(p.z, g[2]) - fmaxf(p.x, g[0]), 0.f);
    float ih = fmaxf(fminf(p.w, g[3]) - fmaxf(p.y, g[1]), 0.f);
    float inter = iw * ih;
    float iou = inter / (a1 + a2 - inter + 1e-16f);
    atomicAdd(&accum[1], x * mm);
    atomicAdd(&accum[2], 1.0f - iou);
    atomicAdd(&accum[3], 1.0f);
}

// ---------- K7: finalize ----------
__global__ void k_final(const float* __restrict__ accum, float* __restrict__ out) {
    float S0 = accum[0], dot = accum[1], box = accum[2], fg = accum[3];
    float ts = fmaxf(fg, 1.0f);
    float cls = (S0 - dot) / ts;
    float lb = (fg > 0.f) ? box / fg : 0.f;
    out[0] = cls + 1.5f * lb;
}

// ---------- launch ----------
extern "C" void kernel_launch(void* const* d_in, const int* in_sizes, int n_in,
                              void* d_out, int out_size, void* d_ws, size_t ws_size,
                              hipStream_t stream) {
    const float* ps = (const float*)d_in[0];   // pred_scores (B,N,NC)
    const float* pd = (const float*)d_in[1];   // pred_dist   (B,N,64)
    const int*   gl = (const int*)  d_in[2];   // gt_labels   (B,M,1)
    const float* gb = (const float*)d_in[3];   // gt_bboxes   (B,M,4)
    const float* w  = (const float*)d_in[4];   // dfl_weight  (16)

    char* ws = (char*)d_ws;
    constexpr size_t PBB_BYTES  = (size_t)BB * NN * 4 * sizeof(float);      // 4.30 MB
    constexpr size_t ALGN_BYTES = (size_t)BB * MM * NN * sizeof(float);     // 43.0 MB
    constexpr size_t MAXM_BYTES = (size_t)BB * NN * sizeof(float);          // 1.08 MB
    constexpr size_t TGT_BYTES  = (size_t)BB * NN * sizeof(int);            // 1.08 MB
    constexpr size_t CV_BYTES   = (size_t)BB * MM * TOPKK * sizeof(float);  // 51 KB

    float* accum = (float*)ws;                                   // 8 floats
    float* pbb   = (float*)(ws + 256);
    float* algn  = (float*)(ws + 256 + PBB_BYTES);
    float* maxm  = (float*)(ws + 256 + PBB_BYTES + ALGN_BYTES);
    int*   tgt   = (int*)  (ws + 256 + PBB_BYTES + ALGN_BYTES + MAXM_BYTES);
    float* cval  = (float*)(ws + 256 + PBB_BYTES + ALGN_BYTES + MAXM_BYTES + TGT_BYTES);
    int*   cidx  = (int*)  (ws + 256 + PBB_BYTES + ALGN_BYTES + MAXM_BYTES + TGT_BYTES + CV_BYTES);

    hipMemsetAsync(accum, 0, 8 * sizeof(float), stream);
    hipMemsetAsync(tgt, 0x7F, TGT_BYTES, stream);   // 0x7F7F7F7F > M

    k_dfl<<<(BB * NN * 4 + 255) / 256, 256, 0, stream>>>(pd, w, pbb);
    dim3 g3((NN + 127) / 128, BB);
    k_align<<<g3, 256, 0, stream>>>(ps, gl, gb, pbb, algn, maxm, accum);
    k_topk<<<BB * MM, 256, 0, stream>>>(algn, cval, cidx);
    k_select<<<(BB * MM * TOPKK + 255) / 256, 256, 0, stream>>>(cval, cidx, maxm, tgt);
    k_fg<<<BB * NN / 256, 256, 0, stream>>>(tgt, gl, gb, ps, pbb, maxm, accum);
    k_final<<<1, 1, 0, stream>>>(accum, (float*)d_out);
}

// Round 2
// 224.173 us; speedup vs baseline: 1.4214x; 1.4214x over previous
//
#include <hip/hip_runtime.h>
#include <cstdint>
#include <cstddef>

#define BB 32
#define NN 8400
#define NCC 80
#define MM 40
#define RM 16
#define TOPKK 10
#define CAP 2048      // max positives per (b,m); measured worst case ~450, 4.5x margin
#define SLOTP 41      // LDS stride for per-slot sigmoid tile; gcd(41,32)=1

// ---------- helpers ----------
__device__ __forceinline__ void anchor_xy(int n, float& ax, float& ay) {
    int s, x, y;
    if (n < 6400)      { s = 8;  y = n / 80;            x = n - y * 80; }
    else if (n < 8000) { int i = n - 6400; s = 16; y = i / 40; x = i - y * 40; }
    else               { int i = n - 8000; s = 32; y = i / 20; x = i - y * 20; }
    ax = ((float)x + 0.5f) * (float)s;
    ay = ((float)y + 0.5f) * (float)s;
}

// ---------- K2: DFL softmax-dot -> pred_bboxes ----------
__global__ __launch_bounds__(256) void k_dfl(const float* __restrict__ pd,
                                             const float* __restrict__ w,
                                             float* __restrict__ pbb) {
    int g = blockIdx.x * 256 + threadIdx.x;
    if (g >= BB * NN * 4) return;
    const float* p = pd + (size_t)g * RM;
    float x[RM];
    #pragma unroll
    for (int i = 0; i < 4; i++) {
        float4 v = *(const float4*)(p + i * 4);
        x[i*4+0] = v.x; x[i*4+1] = v.y; x[i*4+2] = v.z; x[i*4+3] = v.w;
    }
    float mx = x[0];
    #pragma unroll
    for (int i = 1; i < RM; i++) mx = fmaxf(mx, x[i]);
    float s = 0.f, d = 0.f;
    #pragma unroll
    for (int i = 0; i < RM; i++) {
        float e = __builtin_amdgcn_exp2f((x[i] - mx) * 1.44269504f);
        s += e; d += e * w[i];
    }
    float val = d * __builtin_amdgcn_rcpf(s);
    int bn = g >> 2, side = g & 3;
    int n = bn % NN;
    float ax, ay; anchor_xy(n, ax, ay);
    float coord = (side == 0) ? ax - val : (side == 1) ? ay - val
                : (side == 2) ? ax + val : ay + val;
    pbb[g] = coord;
}

// ---------- K3: align tile, sparse candidate push, column-max, softplus sum ----------
// grid: (ceil(N/128), B), 256 threads.
__global__ __launch_bounds__(256) void k_align(const float* __restrict__ ps,
                                               const int*   __restrict__ gl,
                                               const float* __restrict__ gb,
                                               const float* __restrict__ pbb,
                                               float* __restrict__ maxm,
                                               int*   __restrict__ cnts,
                                               unsigned long long* __restrict__ lists,
                                               float* __restrict__ accum) {
    __shared__ float sc[128 * SLOTP];   // sigmoid per (nloc, slot)
    __shared__ float gtb[MM * 4];
    __shared__ int   glab[MM];
    __shared__ int   slotm[MM];
    __shared__ int   cmap[NCC];
    __shared__ float cm[256];
    __shared__ float redf[4];
    const int b  = blockIdx.y;
    const int n0 = blockIdx.x * 128;
    const int t  = threadIdx.x;

    if (t < MM * 4)              gtb[t] = gb[b * MM * 4 + t];
    if (t >= 192 && t < 192+MM)  glab[t - 192] = gl[b * MM + (t - 192)];
    if (t >= 64 && t < 64+NCC)   cmap[t - 64] = -1;
    __syncthreads();
    if (t == 0) {    // serial dedup of 40 labels -> slots (trivial)
        int ns = 0;
        for (int m = 0; m < MM; m++) {
            int c = glab[m];
            if (cmap[c] < 0) cmap[c] = ns++;
            slotm[m] = cmap[c];
        }
    }
    __syncthreads();

    // phase 1: 128x80 score tile; softplus sum for all, sigmoid only for label slots
    float sp = 0.f;
    #pragma unroll
    for (int k = 0; k < 10; k++) {
        int f = t + k * 256;           // [0,2560)
        int row = f / 20, c4 = f - row * 20;
        int n = n0 + row;
        if (n < NN) {
            float4 v = *(const float4*)(ps + ((size_t)(b * NN + n)) * NCC + c4 * 4);
            float xs[4] = {v.x, v.y, v.z, v.w};
            #pragma unroll
            for (int j = 0; j < 4; j++) {
                float x = xs[j];
                float e = __builtin_amdgcn_exp2f(-1.44269504f * fabsf(x));
                float r = __builtin_amdgcn_rcpf(1.0f + e);
                sp += fmaxf(x, 0.f) + 0.69314718f * __builtin_amdgcn_logf(1.0f + e);
                int sl = cmap[c4 * 4 + j];
                if (sl >= 0) sc[row * SLOTP + sl] = (x >= 0.f) ? r : e * r;
            }
        }
    }
    __syncthreads();

    // phase 2: align for 20 gts per thread-half; push positives; running col max
    const int nloc = t & 127;
    const int n    = n0 + nloc;
    const int mb   = (t >> 7) * 20;
    const int lane = t & 63;
    const bool valid = (n < NN);
    float cmax = -INFINITY;
    float px1 = 0, py1 = 0, px2 = 0, py2 = 0, a1 = 0;
    if (valid) {
        float4 p4 = *(const float4*)(pbb + ((size_t)(b * NN + n)) * 4);
        px1 = p4.x; py1 = p4.y; px2 = p4.z; py2 = p4.w;
        a1 = (px2 - px1) * (py2 - py1);
    }
    #pragma unroll
    for (int j = 0; j < 20; j++) {
        int m = mb + j;
        float gx1 = gtb[m*4+0], gy1 = gtb[m*4+1], gx2 = gtb[m*4+2], gy2 = gtb[m*4+3];
        float a2 = (gx2 - gx1) * (gy2 - gy1);
        float iw = fmaxf(fminf(px2, gx2) - fmaxf(px1, gx1), 0.f);
        float ih = fmaxf(fminf(py2, gy2) - fmaxf(py1, gy1), 0.f);
        float inter = iw * ih;
        float iou = fmaxf(inter * __builtin_amdgcn_rcpf(a1 + a2 - inter + 1e-16f), 0.f);
        float al = 0.f;
        if (valid) {
            float sg = sc[nloc * SLOTP + slotm[m]];
            float i2 = iou * iou;
            al = __builtin_amdgcn_sqrtf(sg) * (i2 * i2 * i2);
        }
        cmax = fmaxf(cmax, al);
        // wave-aggregated push of positives to per-(b,m) list
        bool pos = valid && (al > 1e-9f);
        unsigned long long msk = __ballot(pos);
        if (msk) {
            int leader = __ffsll((long long)msk) - 1;
            int basev = 0;
            if (lane == leader) basev = atomicAdd(&cnts[b * MM + m], __popcll(msk));
            basev = __shfl(basev, leader);
            if (pos) {
                int ofs = __popcll(msk & ((1ull << lane) - 1ull));
                int idx = basev + ofs;
                if (idx < CAP)
                    lists[((size_t)(b * MM + m)) * CAP + idx] =
                        ((unsigned long long)__float_as_uint(al) << 32) | (unsigned)n;
            }
        }
    }
    cm[t] = cmax;
    __syncthreads();
    if (t < 128 && valid) maxm[(size_t)b * NN + n] = fmaxf(cm[t], cm[t + 128]);

    // softplus block reduction -> one atomic
    #pragma unroll
    for (int off = 32; off > 0; off >>= 1) sp += __shfl_down(sp, off);
    if ((t & 63) == 0) redf[t >> 6] = sp;
    __syncthreads();
    if (t == 0) atomicAdd(accum, redf[0] + redf[1] + redf[2] + redf[3]);
}

// ---------- K4: top-10 of compacted positives + select, one wave per (b,m) ----------
__global__ __launch_bounds__(64) void k_topk(const unsigned long long* __restrict__ lists,
                                             const int*   __restrict__ cnts,
                                             const float* __restrict__ maxm,
                                             int* __restrict__ tgt) {
    __shared__ unsigned long long keys[CAP];
    const int bm = blockIdx.x, b = bm / MM, m = bm % MM, t = threadIdx.x;
    int cnt = min(cnts[bm], CAP);
    for (int i = t; i < cnt; i += 64) {
        unsigned long long L = lists[(size_t)bm * CAP + i];
        // key: value-major, then min-n tie-break (n unique per list anyway)
        keys[i] = (L & 0xFFFFFFFF00000000ull) | (0xFFFFFFFFull - (L & 0xFFFFFFFFull));
    }
    __syncthreads();
    int kk = min(TOPKK, cnt);
    for (int p = 0; p < kk; p++) {
        unsigned long long best = 0ull;
        for (int i = t; i < cnt; i += 64) best = keys[i] > best ? keys[i] : best;
        #pragma unroll
        for (int off = 32; off > 0; off >>= 1) {
            unsigned long long o = __shfl_xor(best, off);
            best = o > best ? o : best;
        }
        for (int i = t; i < cnt; i += 64) if (keys[i] == best) keys[i] = 0ull;
        if (t == 0) {
            float v = __uint_as_float((unsigned)(best >> 32));
            int n = (int)(0xFFFFFFFFull - (best & 0xFFFFFFFFull));
            if (v == maxm[(size_t)b * NN + n]) atomicMin(&tgt[(size_t)b * NN + n], m);
        }
        __syncthreads();
    }
}

// ---------- K6: fg accumulation (dot, box, count) ----------
__global__ __launch_bounds__(256) void k_fg(const int*   __restrict__ tgt,
                                            const int*   __restrict__ gl,
                                            const float* __restrict__ gb,
                                            const float* __restrict__ ps,
                                            const float* __restrict__ pbb,
                                            const float* __restrict__ maxm,
                                            float* __restrict__ accum) {
    int i = blockIdx.x * 256 + threadIdx.x;   // i in [0, B*N)
    int tg = tgt[i];
    if (tg >= MM) return;
    int b = i / NN;
    int lab = gl[b * MM + tg];
    float x = ps[(size_t)i * NCC + lab];
    float mm = maxm[i];
    float4 p = *(const float4*)(pbb + (size_t)i * 4);
    const float* g = gb + ((size_t)b * MM + tg) * 4;
    float a1 = (p.z - p.x) * (p.w - p.y);
    float a2 = (g[2] - g[0]) * (g[3] - g[1]);
    float iw = fmaxf(fminf(p.z, g[2]) - fmaxf(p.x, g[0]), 0.f);
    float ih = fmaxf(fminf(p.w, g[3]) - fmaxf(p.y, g[1]), 0.f);
    float inter = iw * ih;
    float iou = inter / (a1 + a2 - inter + 1e-16f);
    atomicAdd(&accum[1], x * mm);
    atomicAdd(&accum[2], 1.0f - iou);
    atomicAdd(&accum[3], 1.0f);
}

// ---------- K7: finalize ----------
__global__ void k_final(const float* __restrict__ accum, float* __restrict__ out) {
    float S0 = accum[0], dot = accum[1], box = accum[2], fg = accum[3];
    float ts = fmaxf(fg, 1.0f);
    float cls = (S0 - dot) / ts;
    float lb = (fg > 0.f) ? box / fg : 0.f;
    out[0] = cls + 1.5f * lb;
}

// ---------- launch ----------
extern "C" void kernel_launch(void* const* d_in, const int* in_sizes, int n_in,
                              void* d_out, int out_size, void* d_ws, size_t ws_size,
                              hipStream_t stream) {
    const float* ps = (const float*)d_in[0];   // pred_scores (B,N,NC)
    const float* pd = (const float*)d_in[1];   // pred_dist   (B,N,64)
    const int*   gl = (const int*)  d_in[2];   // gt_labels   (B,M,1)
    const float* gb = (const float*)d_in[3];   // gt_bboxes   (B,M,4)
    const float* w  = (const float*)d_in[4];   // dfl_weight  (16)

    char* ws = (char*)d_ws;
    constexpr size_t PBB_BYTES  = (size_t)BB * NN * 4 * sizeof(float);      // 4.30 MB
    constexpr size_t MAXM_BYTES = (size_t)BB * NN * sizeof(float);          // 1.08 MB
    constexpr size_t TGT_BYTES  = (size_t)BB * NN * sizeof(int);            // 1.08 MB
    constexpr size_t CNT_BYTES  = 8192;                                     // 1280 ints, padded
    constexpr size_t LIST_BYTES = (size_t)BB * MM * CAP * 8;                // 20.97 MB

    float* accum = (float*)ws;                                   // 8 floats
    float* pbb   = (float*)(ws + 256);
    float* maxm  = (float*)(ws + 256 + PBB_BYTES);
    int*   tgt   = (int*)  (ws + 256 + PBB_BYTES + MAXM_BYTES);
    int*   cnts  = (int*)  (ws + 256 + PBB_BYTES + MAXM_BYTES + TGT_BYTES);
    unsigned long long* lists =
        (unsigned long long*)(ws + 256 + PBB_BYTES + MAXM_BYTES + TGT_BYTES + CNT_BYTES);
    (void)LIST_BYTES;

    hipMemsetAsync(accum, 0, 8 * sizeof(float), stream);
    hipMemsetAsync(tgt, 0x7F, TGT_BYTES, stream);   // 0x7F7F7F7F > M
    hipMemsetAsync(cnts, 0, CNT_BYTES, stream);

    k_dfl<<<(BB * NN * 4 + 255) / 256, 256, 0, stream>>>(pd, w, pbb);
    dim3 g3((NN + 127) / 128, BB);
    k_align<<<g3, 256, 0, stream>>>(ps, gl, gb, pbb, maxm, cnts, lists, accum);
    k_topk<<<BB * MM, 64, 0, stream>>>(lists, cnts, maxm, tgt);
    k_fg<<<BB * NN / 256, 256, 0, stream>>>(tgt, gl, gb, ps, pbb, maxm, accum);
    k_final<<<1, 1, 0, stream>>>(accum, (float*)d_out);
}

// Round 3
// 198.667 us; speedup vs baseline: 1.6039x; 1.1284x over previous
//
#include <hip/hip_runtime.h>
#include <cstdint>
#include <cstddef>

#define BB 32
#define NN 8400
#define NCC 80
#define MM 40
#define RM 16
#define TOPKK 10
#define CAP 2048      // max positives per (b,m); measured worst case ~450, 4.5x margin
#define SLOTP 41      // LDS stride for per-slot sigmoid tile; gcd(41,32)=1

// ---------- helpers ----------
__device__ __forceinline__ void anchor_xy(int n, float& ax, float& ay) {
    int s, x, y;
    if (n < 6400)      { s = 8;  y = n / 80;            x = n - y * 80; }
    else if (n < 8000) { int i = n - 6400; s = 16; y = i / 40; x = i - y * 40; }
    else               { int i = n - 8000; s = 32; y = i / 20; x = i - y * 20; }
    ax = ((float)x + 0.5f) * (float)s;
    ay = ((float)y + 0.5f) * (float)s;
}

// ---------- K_main: DFL + sigmoid/softplus tile + align + sparse push ----------
// grid: (ceil(N/128), B), 256 threads.
__global__ __launch_bounds__(256) void k_main(const float* __restrict__ ps,
                                              const float* __restrict__ pd,
                                              const int*   __restrict__ gl,
                                              const float* __restrict__ gb,
                                              const float* __restrict__ w,
                                              float* __restrict__ pbb,
                                              float* __restrict__ maxm,
                                              int*   __restrict__ cnts,
                                              unsigned long long* __restrict__ lists,
                                              float* __restrict__ accum) {
    __shared__ float  sc[128 * SLOTP];   // sigmoid per (nloc, slot)
    __shared__ float4 box[128];          // ltrb then pred box
    __shared__ float  gtb[MM * 4];
    __shared__ int    glab[MM];
    __shared__ int    slotm[MM];
    __shared__ int    cmap[NCC];
    __shared__ float  cm[256];
    __shared__ float  redf[4];
    const int b  = blockIdx.y;
    const int n0 = blockIdx.x * 128;
    const int t  = threadIdx.x;

    if (t < MM * 4)              gtb[t] = gb[b * MM * 4 + t];
    if (t >= 192 && t < 192+MM)  glab[t - 192] = gl[b * MM + (t - 192)];
    if (t >= 64 && t < 64+NCC)   cmap[t - 64] = 0x7FFFFFFF;
    __syncthreads();
    if (t < MM) atomicMin(&cmap[glab[t]], t);   // parallel label dedup
    __syncthreads();
    if (t < MM) slotm[t] = cmap[glab[t]];       // slot = representative m, in [0,MM)

    // ---- phase 0: DFL softmax-dot for this block's 128 anchors (512 sides) ----
    #pragma unroll
    for (int h = 0; h < 2; h++) {
        int f = t + h * 256;                    // (anchor,side) flat in [0,512)
        int a = f >> 2, side = f & 3;
        int nc = min(n0 + a, NN - 1);
        const float* p = pd + (((size_t)(b * NN + nc)) * 4 + side) * RM;
        float x[RM];
        #pragma unroll
        for (int i = 0; i < 4; i++) {
            float4 v = *(const float4*)(p + i * 4);
            x[i*4+0] = v.x; x[i*4+1] = v.y; x[i*4+2] = v.z; x[i*4+3] = v.w;
        }
        float mx = x[0];
        #pragma unroll
        for (int i = 1; i < RM; i++) mx = fmaxf(mx, x[i]);
        float s = 0.f, d = 0.f;
        #pragma unroll
        for (int i = 0; i < RM; i++) {
            float e = __builtin_amdgcn_exp2f((x[i] - mx) * 1.44269504f);
            s += e; d += e * w[i];
        }
        ((float*)box)[f] = d * __builtin_amdgcn_rcpf(s);
    }
    __syncthreads();
    if (t < 128) {
        int n = n0 + t;
        float ax, ay; anchor_xy(min(n, NN - 1), ax, ay);
        float4 v = box[t];
        float4 pb = make_float4(ax - v.x, ay - v.y, ax + v.z, ay + v.w);
        box[t] = pb;
        if (n < NN) *(float4*)(pbb + (size_t)(b * NN + n) * 4) = pb;
    }

    // ---- phase 1: 128x80 score tile; batched loads for ILP ----
    float4 vv[10];
    #pragma unroll
    for (int k = 0; k < 10; k++) {
        int f = t + k * 256;                    // [0,2560)
        int row = f / 20, c4 = f - row * 20;
        int nc = min(n0 + row, NN - 1);
        vv[k] = *(const float4*)(ps + ((size_t)(b * NN + nc)) * NCC + c4 * 4);
    }
    float sp = 0.f;
    #pragma unroll
    for (int k = 0; k < 10; k++) {
        int f = t + k * 256;
        int row = f / 20, c4 = f - row * 20;
        float vmask = (n0 + row < NN) ? 1.f : 0.f;
        float xs[4] = {vv[k].x, vv[k].y, vv[k].z, vv[k].w};
        #pragma unroll
        for (int j = 0; j < 4; j++) {
            float x = xs[j];
            float e = __builtin_amdgcn_exp2f(-1.44269504f * fabsf(x));
            float r = __builtin_amdgcn_rcpf(1.0f + e);
            sp += vmask * (fmaxf(x, 0.f) + 0.69314718f * __builtin_amdgcn_logf(1.0f + e));
            int sl = cmap[c4 * 4 + j];
            if (sl < MM) sc[row * SLOTP + sl] = (x >= 0.f) ? r : e * r;
        }
    }
    __syncthreads();

    // ---- phase 2: align for 20 gts per thread-half; push positives; col max ----
    const int nloc = t & 127;
    const int n    = n0 + nloc;
    const int mb   = (t >> 7) * 20;
    const int lane = t & 63;
    const bool valid = (n < NN);
    float cmax = -INFINITY;
    float4 p4 = box[nloc];
    const float px1 = p4.x, py1 = p4.y, px2 = p4.z, py2 = p4.w;
    const float a1 = (px2 - px1) * (py2 - py1);
    #pragma unroll
    for (int j = 0; j < 20; j++) {
        int m = mb + j;
        float gx1 = gtb[m*4+0], gy1 = gtb[m*4+1], gx2 = gtb[m*4+2], gy2 = gtb[m*4+3];
        float a2 = (gx2 - gx1) * (gy2 - gy1);
        float iw = fmaxf(fminf(px2, gx2) - fmaxf(px1, gx1), 0.f);
        float ih = fmaxf(fminf(py2, gy2) - fmaxf(py1, gy1), 0.f);
        float inter = iw * ih;
        float iou = fmaxf(inter * __builtin_amdgcn_rcpf(a1 + a2 - inter + 1e-16f), 0.f);
        float al = 0.f;
        if (valid) {
            float sg = sc[nloc * SLOTP + slotm[m]];
            float i2 = iou * iou;
            al = __builtin_amdgcn_sqrtf(sg) * (i2 * i2 * i2);
        }
        cmax = fmaxf(cmax, al);
        bool pos = valid && (al > 1e-9f);
        unsigned long long msk = __ballot(pos);
        if (msk) {
            int leader = __ffsll((long long)msk) - 1;
            int basev = 0;
            if (lane == leader) basev = atomicAdd(&cnts[b * MM + m], __popcll(msk));
            basev = __shfl(basev, leader);
            if (pos) {
                int ofs = __popcll(msk & ((1ull << lane) - 1ull));
                int idx = basev + ofs;
                if (idx < CAP)
                    lists[((size_t)(b * MM + m)) * CAP + idx] =
                        ((unsigned long long)__float_as_uint(al) << 32) | (unsigned)n;
            }
        }
    }
    cm[t] = cmax;
    __syncthreads();
    if (t < 128 && valid) maxm[(size_t)b * NN + n] = fmaxf(cm[t], cm[t + 128]);

    // softplus block reduction -> one atomic
    #pragma unroll
    for (int off = 32; off > 0; off >>= 1) sp += __shfl_down(sp, off);
    if ((t & 63) == 0) redf[t >> 6] = sp;
    __syncthreads();
    if (t == 0) atomicAdd(accum, redf[0] + redf[1] + redf[2] + redf[3]);
}

// ---------- K_topk: top-10 of compacted positives, LDS-only passes ----------
__global__ __launch_bounds__(64) void k_topk(const unsigned long long* __restrict__ lists,
                                             const int*   __restrict__ cnts,
                                             const float* __restrict__ maxm,
                                             int* __restrict__ tgt) {
    __shared__ unsigned long long keys[CAP];
    __shared__ unsigned long long sel[TOPKK];
    const int bm = blockIdx.x, b = bm / MM, m = bm % MM, t = threadIdx.x;
    int cnt = min(cnts[bm], CAP);
    int kk = min(TOPKK, cnt);
    for (int i = t; i < cnt; i += 64) {
        unsigned long long L = lists[(size_t)bm * CAP + i];
        keys[i] = (L & 0xFFFFFFFF00000000ull) | (0xFFFFFFFFull - (L & 0xFFFFFFFFull));
    }
    __syncthreads();
    for (int p = 0; p < kk; p++) {
        unsigned long long best = 0ull;
        for (int i = t; i < cnt; i += 64) best = keys[i] > best ? keys[i] : best;
        #pragma unroll
        for (int off = 32; off > 0; off >>= 1) {
            unsigned long long o = __shfl_xor(best, off);
            best = o > best ? o : best;
        }
        for (int i = t; i < cnt; i += 64) if (keys[i] == best) keys[i] = 0ull;
        if (t == 0) sel[p] = best;
        __syncthreads();
    }
    if (t < kk) {
        unsigned long long bb = sel[t];
        float v = __uint_as_float((unsigned)(bb >> 32));
        int n = (int)(0xFFFFFFFFull - (bb & 0xFFFFFFFFull));
        if (v == maxm[(size_t)b * NN + n]) atomicMin(&tgt[(size_t)b * NN + n], m);
    }
}

// ---------- K_fg: fg accumulation with block reduction ----------
__global__ __launch_bounds__(256) void k_fg(const int*   __restrict__ tgt,
                                            const int*   __restrict__ gl,
                                            const float* __restrict__ gb,
                                            const float* __restrict__ ps,
                                            const float* __restrict__ pbb,
                                            const float* __restrict__ maxm,
                                            float* __restrict__ accum) {
    int i = blockIdx.x * 256 + threadIdx.x;   // i in [0, B*N)
    int t = threadIdx.x;
    float vdot = 0.f, vbox = 0.f, vfg = 0.f;
    int tg = tgt[i];
    if (tg < MM) {
        int b = i / NN;
        int lab = gl[b * MM + tg];
        float x = ps[(size_t)i * NCC + lab];
        float mm = maxm[i];
        float4 p = *(const float4*)(pbb + (size_t)i * 4);
        const float* g = gb + ((size_t)b * MM + tg) * 4;
        float a1 = (p.z - p.x) * (p.w - p.y);
        float a2 = (g[2] - g[0]) * (g[3] - g[1]);
        float iw = fmaxf(fminf(p.z, g[2]) - fmaxf(p.x, g[0]), 0.f);
        float ih = fmaxf(fminf(p.w, g[3]) - fmaxf(p.y, g[1]), 0.f);
        float inter = iw * ih;
        float iou = inter / (a1 + a2 - inter + 1e-16f);
        vdot = x * mm; vbox = 1.0f - iou; vfg = 1.0f;
    }
    #pragma unroll
    for (int off = 32; off > 0; off >>= 1) {
        vdot += __shfl_down(vdot, off);
        vbox += __shfl_down(vbox, off);
        vfg  += __shfl_down(vfg,  off);
    }
    __shared__ float r[3][4];
    if ((t & 63) == 0) { int wv = t >> 6; r[0][wv] = vdot; r[1][wv] = vbox; r[2][wv] = vfg; }
    __syncthreads();
    if (t < 3) {
        float s = r[t][0] + r[t][1] + r[t][2] + r[t][3];
        if (s != 0.f) atomicAdd(&accum[1 + t], s);
    }
}

// ---------- K_final ----------
__global__ void k_final(const float* __restrict__ accum, float* __restrict__ out) {
    float S0 = accum[0], dot = accum[1], box = accum[2], fg = accum[3];
    float ts = fmaxf(fg, 1.0f);
    float cls = (S0 - dot) / ts;
    float lb = (fg > 0.f) ? box / fg : 0.f;
    out[0] = cls + 1.5f * lb;
}

// ---------- launch ----------
extern "C" void kernel_launch(void* const* d_in, const int* in_sizes, int n_in,
                              void* d_out, int out_size, void* d_ws, size_t ws_size,
                              hipStream_t stream) {
    const float* ps = (const float*)d_in[0];   // pred_scores (B,N,NC)
    const float* pd = (const float*)d_in[1];   // pred_dist   (B,N,64)
    const int*   gl = (const int*)  d_in[2];   // gt_labels   (B,M,1)
    const float* gb = (const float*)d_in[3];   // gt_bboxes   (B,M,4)
    const float* w  = (const float*)d_in[4];   // dfl_weight  (16)

    char* ws = (char*)d_ws;
    constexpr size_t PBB_BYTES  = (size_t)BB * NN * 4 * sizeof(float);      // 4.30 MB
    constexpr size_t MAXM_BYTES = (size_t)BB * NN * sizeof(float);          // 1.08 MB
    constexpr size_t TGT_BYTES  = (size_t)BB * NN * sizeof(int);            // 1.08 MB
    constexpr size_t CNT_BYTES  = 8192;                                     // 1280 ints, padded

    float* accum = (float*)ws;                                   // 8 floats
    float* pbb   = (float*)(ws + 256);
    float* maxm  = (float*)(ws + 256 + PBB_BYTES);
    int*   tgt   = (int*)  (ws + 256 + PBB_BYTES + MAXM_BYTES);
    int*   cnts  = (int*)  (ws + 256 + PBB_BYTES + MAXM_BYTES + TGT_BYTES);
    unsigned long long* lists =
        (unsigned long long*)(ws + 256 + PBB_BYTES + MAXM_BYTES + TGT_BYTES + CNT_BYTES);

    hipMemsetAsync(accum, 0, 8 * sizeof(float), stream);
    hipMemsetAsync(tgt, 0x7F, TGT_BYTES, stream);   // 0x7F7F7F7F > M
    hipMemsetAsync(cnts, 0, CNT_BYTES, stream);

    dim3 g3((NN + 127) / 128, BB);
    k_main<<<g3, 256, 0, stream>>>(ps, pd, gl, gb, w, pbb, maxm, cnts, lists, accum);
    k_topk<<<BB * MM, 64, 0, stream>>>(lists, cnts, maxm, tgt);
    k_fg<<<BB * NN / 256, 256, 0, stream>>>(tgt, gl, gb, ps, pbb, maxm, accum);
    k_final<<<1, 1, 0, stream>>>(accum, (float*)d_out);
}